// Round 1
// baseline (434.725 us; speedup 1.0000x reference)
//
#include <hip/hip_runtime.h>
#include <hip/hip_bf16.h>
#include <math.h>

// ViT Vector Quantizer: z [32,1024,32] f32, embedding [8192,32] f32.
// Outputs (concat, all read as f32): z_q_out [N*D], loss [1], idx [N] (as float values).
//
// Pipeline:
//   K0: normalize embedding rows -> en, en_sq   (ws)
//   K1: per-row argmin over d = (|zf|^2 + |en_k|^2) - 2 zf.en_k, K split 8 ways,
//       merged via 64-bit atomicMin on (orderable(d)<<32 | k)  -> first-min semantics
//   K2: gather en[idx], write z_q_out = z + (en[idx]-z), idx, and loss = 1.25*mean((en[idx]-zf)^2)

#define D 32
#define EPS 1e-12f

__global__ __launch_bounds__(256) void k_norm_emb(const float* __restrict__ e,
                                                  float* __restrict__ en,
                                                  float* __restrict__ en_sq,
                                                  int K) {
  int row = blockIdx.x * 256 + threadIdx.x;
  if (row >= K) return;
  const float4* p = reinterpret_cast<const float4*>(e + (size_t)row * D);
  float v[D];
#pragma unroll
  for (int j = 0; j < D / 4; ++j) {
    float4 q = p[j];
    v[4 * j + 0] = q.x; v[4 * j + 1] = q.y; v[4 * j + 2] = q.z; v[4 * j + 3] = q.w;
  }
  float ss = 0.f;
#pragma unroll
  for (int d = 0; d < D; ++d) ss = fmaf(v[d], v[d], ss);
  float n = fmaxf(sqrtf(ss), EPS);
  float s2 = 0.f;
  float4* o = reinterpret_cast<float4*>(en + (size_t)row * D);
#pragma unroll
  for (int j = 0; j < D / 4; ++j) {
    float4 q;
    q.x = v[4 * j + 0] / n;  // true division to mirror reference x / max(n,eps)
    q.y = v[4 * j + 1] / n;
    q.z = v[4 * j + 2] / n;
    q.w = v[4 * j + 3] / n;
    s2 = fmaf(q.x, q.x, fmaf(q.y, q.y, fmaf(q.z, q.z, fmaf(q.w, q.w, s2))));
    o[j] = q;
  }
  en_sq[row] = s2;
}

__global__ __launch_bounds__(256) void k_argmin(const float* __restrict__ z,
                                                const float* __restrict__ en,
                                                const float* __restrict__ en_sq,
                                                unsigned long long* __restrict__ mp,
                                                int kchunk) {
  int row = blockIdx.x * 256 + threadIdx.x;
  int k0 = blockIdx.y * kchunk;

  const float4* p = reinterpret_cast<const float4*>(z + (size_t)row * D);
  float v[D];
#pragma unroll
  for (int j = 0; j < D / 4; ++j) {
    float4 q = p[j];
    v[4 * j + 0] = q.x; v[4 * j + 1] = q.y; v[4 * j + 2] = q.z; v[4 * j + 3] = q.w;
  }
  float ss = 0.f;
#pragma unroll
  for (int d = 0; d < D; ++d) ss = fmaf(v[d], v[d], ss);
  float n = fmaxf(sqrtf(ss), EPS);
#pragma unroll
  for (int d = 0; d < D; ++d) v[d] = v[d] / n;
  float zsq = 0.f;
#pragma unroll
  for (int d = 0; d < D; ++d) zsq = fmaf(v[d], v[d], zsq);

  float dmin = 3.4e38f;
  int kb = k0;
  // k, and therefore all en/en_sq addresses, are wave-uniform -> scalar loads.
#pragma unroll 2
  for (int k = k0; k < k0 + kchunk; ++k) {
    const float* __restrict__ er = en + (size_t)k * D;
    float a0 = 0.f, a1 = 0.f, a2 = 0.f, a3 = 0.f;
#pragma unroll
    for (int j = 0; j < D; j += 4) {
      a0 = fmaf(v[j + 0], er[j + 0], a0);
      a1 = fmaf(v[j + 1], er[j + 1], a1);
      a2 = fmaf(v[j + 2], er[j + 2], a2);
      a3 = fmaf(v[j + 3], er[j + 3], a3);
    }
    float dot = (a0 + a1) + (a2 + a3);
    float dd = fmaf(-2.0f, dot, zsq + en_sq[k]);  // (zsq+esq) - 2*dot, one rounding
    if (dd < dmin) { dmin = dd; kb = k; }         // strict < keeps first minimum
  }

  unsigned key = __float_as_uint(dmin);
  key = (key & 0x80000000u) ? ~key : (key | 0x80000000u);  // total order as uint
  unsigned long long packed =
      ((unsigned long long)key << 32) | (unsigned long long)(unsigned)kb;
  atomicMin(&mp[row], packed);
}

__global__ __launch_bounds__(256) void k_epi(const float* __restrict__ z,
                                             const float* __restrict__ en,
                                             const unsigned long long* __restrict__ mp,
                                             float* __restrict__ out_z,
                                             float* __restrict__ loss,
                                             float* __restrict__ out_idx,
                                             float scale) {
  int row = blockIdx.x * 256 + threadIdx.x;
  int kb = (int)(unsigned)(mp[row] & 0xFFFFFFFFull);
  out_idx[row] = (float)kb;  // whole out buffer is read back as f32

  const float4* p = reinterpret_cast<const float4*>(z + (size_t)row * D);
  float4 q[D / 4];
#pragma unroll
  for (int j = 0; j < D / 4; ++j) q[j] = p[j];
  float ss = 0.f;
#pragma unroll
  for (int j = 0; j < D / 4; ++j)
    ss = fmaf(q[j].x, q[j].x, fmaf(q[j].y, q[j].y, fmaf(q[j].z, q[j].z, fmaf(q[j].w, q[j].w, ss))));
  float n = fmaxf(sqrtf(ss), EPS);

  const float4* ep = reinterpret_cast<const float4*>(en + (size_t)kb * D);
  float4* op = reinterpret_cast<float4*>(out_z + (size_t)row * D);
  float s = 0.f;
#pragma unroll
  for (int j = 0; j < D / 4; ++j) {
    float4 e = ep[j];
    float4 o;
    o.x = q[j].x + (e.x - q[j].x);  // STE forward value, reference op order
    o.y = q[j].y + (e.y - q[j].y);
    o.z = q[j].z + (e.z - q[j].z);
    o.w = q[j].w + (e.w - q[j].w);
    op[j] = o;
    float dx = e.x - q[j].x / n;  float dy = e.y - q[j].y / n;
    float dz = e.z - q[j].z / n;  float dw = e.w - q[j].w / n;
    s = fmaf(dx, dx, fmaf(dy, dy, fmaf(dz, dz, fmaf(dw, dw, s))));
  }

  // block-reduce s, one atomicAdd per block
#pragma unroll
  for (int off = 32; off > 0; off >>= 1) s += __shfl_down(s, off, 64);
  __shared__ float wsum[4];
  int lane = threadIdx.x & 63, wid = threadIdx.x >> 6;
  if (lane == 0) wsum[wid] = s;
  __syncthreads();
  if (threadIdx.x == 0) {
    float t = (wsum[0] + wsum[1]) + (wsum[2] + wsum[3]);
    atomicAdd(loss, t * scale);
  }
}

extern "C" void kernel_launch(void* const* d_in, const int* in_sizes, int n_in,
                              void* d_out, int out_size, void* d_ws, size_t ws_size,
                              hipStream_t stream) {
  const float* z = (const float*)d_in[0];
  const float* emb = (const float*)d_in[1];
  const int N = in_sizes[0] / D;  // 32768
  const int K = in_sizes[1] / D;  // 8192

  float* out = (float*)d_out;
  float* out_z = out;                          // N*D
  float* loss = out + (size_t)N * D;           // 1
  float* out_idx = out + (size_t)N * D + 1;    // N

  float* en = (float*)d_ws;                                  // K*D f32
  float* en_sq = en + (size_t)K * D;                         // K f32
  unsigned long long* mp =
      (unsigned long long*)(en_sq + K);                      // N u64 (8B aligned)

  hipMemsetAsync(mp, 0xFF, (size_t)N * sizeof(unsigned long long), stream);
  hipMemsetAsync(loss, 0, sizeof(float), stream);

  k_norm_emb<<<dim3((K + 255) / 256), 256, 0, stream>>>(emb, en, en_sq, K);

  const int KSPLIT = 8;
  k_argmin<<<dim3(N / 256, KSPLIT), 256, 0, stream>>>(z, en, en_sq, mp, K / KSPLIT);

  k_epi<<<dim3(N / 256), 256, 0, stream>>>(z, en, mp, out_z, loss, out_idx,
                                           1.25f / (float)((size_t)N * D));
}

// Round 2
// 321.821 us; speedup vs baseline: 1.3508x; 1.3508x over previous
//
#include <hip/hip_runtime.h>
#include <hip/hip_bf16.h>
#include <math.h>

// ViT Vector Quantizer: z [32,1024,32] f32, embedding [8192,32] f32.
// Outputs (concat, read as f32): z_q_out [N*D], loss [1], idx [N] (as floats).
//
// R2 structure:
//   K0 k_norm_emb : normalize codebook -> en, en_sq; zero loss; (init mp if atomic mode)
//   K1 k_argmin   : 4 rows/thread register-blocked dot products vs wave-uniform
//                   scalar-loaded en rows; partial argmin per K-split written as
//                   packed (orderable_d << 32 | k) -- plain stores, no atomics
//                   (falls back to atomicMin if ws too small for partials)
//   K2 k_epi      : min-reduce partials, gather en[idx], write z_q_out, idx, loss

#define D 32
#define RPT 4           // rows per thread in k_argmin
#define EPS 1e-12f

__global__ __launch_bounds__(256) void k_norm_emb(const float* __restrict__ e,
                                                  float* __restrict__ en,
                                                  float* __restrict__ en_sq,
                                                  int K,
                                                  unsigned long long* __restrict__ mp,
                                                  int mp_init_count,
                                                  float* __restrict__ loss) {
  int row = blockIdx.x * 256 + threadIdx.x;
  if (row == 0) *loss = 0.f;
  for (int i = row; i < mp_init_count; i += gridDim.x * 256)
    mp[i] = ~0ull;                      // +inf key (atomic-fallback mode only)
  if (row >= K) return;

  const float4* p = reinterpret_cast<const float4*>(e + (size_t)row * D);
  float v[D];
#pragma unroll
  for (int j = 0; j < D / 4; ++j) {
    float4 q = p[j];
    v[4 * j + 0] = q.x; v[4 * j + 1] = q.y; v[4 * j + 2] = q.z; v[4 * j + 3] = q.w;
  }
  float ss = 0.f;
#pragma unroll
  for (int d = 0; d < D; ++d) ss = fmaf(v[d], v[d], ss);
  float n = fmaxf(sqrtf(ss), EPS);
  float s2 = 0.f;
  float4* o = reinterpret_cast<float4*>(en + (size_t)row * D);
#pragma unroll
  for (int j = 0; j < D / 4; ++j) {
    float4 q;
    q.x = v[4 * j + 0] / n;   // true division mirrors reference x / max(n,eps)
    q.y = v[4 * j + 1] / n;
    q.z = v[4 * j + 2] / n;
    q.w = v[4 * j + 3] / n;
    s2 = fmaf(q.x, q.x, fmaf(q.y, q.y, fmaf(q.z, q.z, fmaf(q.w, q.w, s2))));
    o[j] = q;
  }
  en_sq[row] = s2;
}

// 4 rows/thread: one wave-uniform en row (scalar loads) feeds 128 FMAs.
// VGPR ~150 -> ~3 waves/SIMD cap; grid gives 8 waves/CU. ILP does the hiding.
__global__ __launch_bounds__(256, 2) void k_argmin(const float* __restrict__ z,
                                                   const float* __restrict__ en,
                                                   const float* __restrict__ en_sq,
                                                   unsigned long long* __restrict__ mp,
                                                   int kchunk, int N, int mode) {
  const int t = threadIdx.x;
  const int rowbase = blockIdx.x * (256 * RPT);
  const int k0 = blockIdx.y * kchunk;

  float v[RPT][D];
  float zsq[RPT];
#pragma unroll
  for (int r = 0; r < RPT; ++r) {
    int row = rowbase + r * 256 + t;          // strided: coalesced float4 loads
    const float4* p = reinterpret_cast<const float4*>(z + (size_t)row * D);
#pragma unroll
    for (int j = 0; j < D / 4; ++j) {
      float4 q = p[j];
      v[r][4 * j + 0] = q.x; v[r][4 * j + 1] = q.y;
      v[r][4 * j + 2] = q.z; v[r][4 * j + 3] = q.w;
    }
    float ss = 0.f;
#pragma unroll
    for (int d = 0; d < D; ++d) ss = fmaf(v[r][d], v[r][d], ss);
    float n = fmaxf(sqrtf(ss), EPS);
#pragma unroll
    for (int d = 0; d < D; ++d) v[r][d] = v[r][d] / n;
    float s2 = 0.f;
#pragma unroll
    for (int d = 0; d < D; ++d) s2 = fmaf(v[r][d], v[r][d], s2);
    zsq[r] = s2;
  }

  float dmin[RPT];
  int kb[RPT];
#pragma unroll
  for (int r = 0; r < RPT; ++r) { dmin[r] = 3.4e38f; kb[r] = k0; }

#pragma unroll 2
  for (int k = k0; k < k0 + kchunk; ++k) {
    const float* __restrict__ er = en + (size_t)k * D;  // wave-uniform -> s_load
    float esq = en_sq[k];                               // scalar
    float a0 = 0.f, a1 = 0.f, a2 = 0.f, a3 = 0.f;
#pragma unroll
    for (int j = 0; j < D; ++j) {
      float e = er[j];
      a0 = fmaf(v[0][j], e, a0);   // 4 independent chains: dep distance 8 cyc
      a1 = fmaf(v[1][j], e, a1);   // > 4 cyc FMA latency -> no stall
      a2 = fmaf(v[2][j], e, a2);
      a3 = fmaf(v[3][j], e, a3);
    }
    float d0 = fmaf(-2.f, a0, zsq[0] + esq);
    float d1 = fmaf(-2.f, a1, zsq[1] + esq);
    float d2 = fmaf(-2.f, a2, zsq[2] + esq);
    float d3 = fmaf(-2.f, a3, zsq[3] + esq);
    if (d0 < dmin[0]) { dmin[0] = d0; kb[0] = k; }  // strict < keeps first min
    if (d1 < dmin[1]) { dmin[1] = d1; kb[1] = k; }
    if (d2 < dmin[2]) { dmin[2] = d2; kb[2] = k; }
    if (d3 < dmin[3]) { dmin[3] = d3; kb[3] = k; }
  }

#pragma unroll
  for (int r = 0; r < RPT; ++r) {
    unsigned key = __float_as_uint(dmin[r]);
    key = (key & 0x80000000u) ? ~key : (key | 0x80000000u);  // total order
    unsigned long long pk =
        ((unsigned long long)key << 32) | (unsigned long long)(unsigned)kb[r];
    if (mode == 0) {
      mp[(size_t)blockIdx.y * N + rowbase + r * 256 + t] = pk;  // coalesced store
    } else {
      atomicMin(&mp[rowbase + r * 256 + t], pk);
    }
  }
}

__global__ __launch_bounds__(256) void k_epi(const float* __restrict__ z,
                                             const float* __restrict__ en,
                                             const unsigned long long* __restrict__ mp,
                                             int nsplit, int N,
                                             float* __restrict__ out_z,
                                             float* __restrict__ loss,
                                             float* __restrict__ out_idx,
                                             float scale) {
  int row = blockIdx.x * 256 + threadIdx.x;
  unsigned long long m = mp[row];
  for (int s = 1; s < nsplit; ++s) {
    unsigned long long m2 = mp[(size_t)s * N + row];
    m = (m2 < m) ? m2 : m;     // min key -> min d, tie -> min k (first occurrence)
  }
  int kb = (int)(unsigned)(m & 0xFFFFFFFFull);
  out_idx[row] = (float)kb;    // whole out buffer read back as f32

  const float4* p = reinterpret_cast<const float4*>(z + (size_t)row * D);
  float4 q[D / 4];
#pragma unroll
  for (int j = 0; j < D / 4; ++j) q[j] = p[j];
  float ss = 0.f;
#pragma unroll
  for (int j = 0; j < D / 4; ++j)
    ss = fmaf(q[j].x, q[j].x, fmaf(q[j].y, q[j].y, fmaf(q[j].z, q[j].z, fmaf(q[j].w, q[j].w, ss))));
  float n = fmaxf(sqrtf(ss), EPS);

  const float4* ep = reinterpret_cast<const float4*>(en + (size_t)kb * D);
  float4* op = reinterpret_cast<float4*>(out_z + (size_t)row * D);
  float s = 0.f;
#pragma unroll
  for (int j = 0; j < D / 4; ++j) {
    float4 e = ep[j];
    float4 o;
    o.x = q[j].x + (e.x - q[j].x);  // STE forward value, reference op order
    o.y = q[j].y + (e.y - q[j].y);
    o.z = q[j].z + (e.z - q[j].z);
    o.w = q[j].w + (e.w - q[j].w);
    op[j] = o;
    float dx = e.x - q[j].x / n;  float dy = e.y - q[j].y / n;
    float dz = e.z - q[j].z / n;  float dw = e.w - q[j].w / n;
    s = fmaf(dx, dx, fmaf(dy, dy, fmaf(dz, dz, fmaf(dw, dw, s))));
  }

#pragma unroll
  for (int off = 32; off > 0; off >>= 1) s += __shfl_down(s, off, 64);
  __shared__ float wsum[4];
  int lane = threadIdx.x & 63, wid = threadIdx.x >> 6;
  if (lane == 0) wsum[wid] = s;
  __syncthreads();
  if (threadIdx.x == 0) {
    float tt = (wsum[0] + wsum[1]) + (wsum[2] + wsum[3]);
    atomicAdd(loss, tt * scale);
  }
}

extern "C" void kernel_launch(void* const* d_in, const int* in_sizes, int n_in,
                              void* d_out, int out_size, void* d_ws, size_t ws_size,
                              hipStream_t stream) {
  const float* z = (const float*)d_in[0];
  const float* emb = (const float*)d_in[1];
  const int N = in_sizes[0] / D;  // 32768
  const int K = in_sizes[1] / D;  // 8192

  float* out = (float*)d_out;
  float* out_z = out;                        // N*D
  float* loss = out + (size_t)N * D;         // 1
  float* out_idx = out + (size_t)N * D + 1;  // N

  float* en = (float*)d_ws;                  // K*D f32   (1 MB)
  float* en_sq = en + (size_t)K * D;         // K f32     (32 KB)
  unsigned long long* mp =
      (unsigned long long*)(en_sq + K);      // partials  (8B-aligned offset)

  const int KSPLIT = 16;
  size_t need = (size_t)K * D * 4 + (size_t)K * 4 + (size_t)KSPLIT * N * 8;
  int mode = (ws_size != 0 && ws_size < need) ? 1 : 0;  // 1 = atomic fallback

  k_norm_emb<<<dim3((K + 255) / 256), 256, 0, stream>>>(
      emb, en, en_sq, K, mp, mode ? N : 0, loss);

  k_argmin<<<dim3(N / (256 * RPT), KSPLIT), 256, 0, stream>>>(
      z, en, en_sq, mp, K / KSPLIT, N, mode);

  k_epi<<<dim3(N / 256), 256, 0, stream>>>(
      z, en, mp, mode ? 1 : KSPLIT, N, out_z, loss, out_idx,
      1.25f / (float)((size_t)N * D));
}

// Round 3
// 284.650 us; speedup vs baseline: 1.5272x; 1.1306x over previous
//
#include <hip/hip_runtime.h>
#include <hip/hip_bf16.h>
#include <math.h>

// ViT Vector Quantizer: z [32,1024,32] f32, embedding [8192,32] f32.
// Outputs (concat, read as f32): z_q_out [N*D], loss [1], idx [N] (as floats).
//
// R3 structure:
//   K0 k_norm_emb : normalize codebook -> en, h=0.5*|en|^2; zero loss; (init mp atomic mode)
//   K1 k_argmin   : block stages its 256-row en chunk into LDS (32 KB) once;
//                   4 rows/thread, argmax of s = en.zf - 0.5|en|^2 (== argmin d,
//                   d = zsq - 2s exactly); per-split result packed
//                   (~orderable(s) << 32 | k), min-merge -> first-min semantics.
//   K2 k_epi      : min-reduce partials, gather en[idx], write z_q_out, idx, loss

#define D 32
#define RPT 4            // rows per thread in k_argmin
#define KCHUNK 256       // codebook rows staged in LDS per block (32 KB)
#define EPS 1e-12f

__global__ __launch_bounds__(256) void k_norm_emb(const float* __restrict__ e,
                                                  float* __restrict__ en,
                                                  float* __restrict__ en_h,
                                                  int K,
                                                  unsigned long long* __restrict__ mp,
                                                  int mp_init_count,
                                                  float* __restrict__ loss) {
  int row = blockIdx.x * 256 + threadIdx.x;
  if (row == 0) *loss = 0.f;
  for (int i = row; i < mp_init_count; i += gridDim.x * 256)
    mp[i] = ~0ull;                      // +inf key (atomic-fallback mode only)
  if (row >= K) return;

  const float4* p = reinterpret_cast<const float4*>(e + (size_t)row * D);
  float v[D];
#pragma unroll
  for (int j = 0; j < D / 4; ++j) {
    float4 q = p[j];
    v[4 * j + 0] = q.x; v[4 * j + 1] = q.y; v[4 * j + 2] = q.z; v[4 * j + 3] = q.w;
  }
  float ss = 0.f;
#pragma unroll
  for (int d = 0; d < D; ++d) ss = fmaf(v[d], v[d], ss);
  float n = fmaxf(sqrtf(ss), EPS);
  float s2 = 0.f;
  float4* o = reinterpret_cast<float4*>(en + (size_t)row * D);
#pragma unroll
  for (int j = 0; j < D / 4; ++j) {
    float4 q;
    q.x = v[4 * j + 0] / n;   // true division mirrors reference x / max(n,eps)
    q.y = v[4 * j + 1] / n;
    q.z = v[4 * j + 2] / n;
    q.w = v[4 * j + 3] / n;
    s2 = fmaf(q.x, q.x, fmaf(q.y, q.y, fmaf(q.z, q.z, fmaf(q.w, q.w, s2))));
    o[j] = q;
  }
  en_h[row] = 0.5f * s2;      // exact halving; d = zsq + 2h - 2(s+h) = zsq - 2s
}

// LDS-staged codebook chunk; wave-uniform ds_read_b128 broadcasts (conflict-free).
// MODE 0: plain store of per-split packed argmin; MODE 1: atomicMin fallback.
template <int MODE>
__global__ __launch_bounds__(256, 3) void k_argmin(const float* __restrict__ z,
                                                   const float* __restrict__ en,
                                                   const float* __restrict__ en_h,
                                                   unsigned long long* __restrict__ mp,
                                                   int N) {
  __shared__ float4 se4[KCHUNK * (D / 4)];   // 32 KB
  __shared__ float sh[KCHUNK];               // 1 KB

  const int t = threadIdx.x;
  const int rowbase = blockIdx.x * (256 * RPT);
  const int k0 = blockIdx.y * KCHUNK;

  // --- one-time cooperative staging: 256 en rows + their h, coalesced ---
  {
    const float4* gsrc = reinterpret_cast<const float4*>(en + (size_t)k0 * D);
#pragma unroll
    for (int i = 0; i < KCHUNK * (D / 4) / 256; ++i)
      se4[i * 256 + t] = gsrc[i * 256 + t];
    sh[t] = en_h[k0 + t];                    // KCHUNK == 256
  }

  // --- load + normalize 4 z rows while the staging settles ---
  float v[RPT][D];
#pragma unroll
  for (int r = 0; r < RPT; ++r) {
    int row = rowbase + r * 256 + t;         // strided: coalesced float4 loads
    const float4* p = reinterpret_cast<const float4*>(z + (size_t)row * D);
#pragma unroll
    for (int j = 0; j < D / 4; ++j) {
      float4 q = p[j];
      v[r][4 * j + 0] = q.x; v[r][4 * j + 1] = q.y;
      v[r][4 * j + 2] = q.z; v[r][4 * j + 3] = q.w;
    }
    float ss = 0.f;
#pragma unroll
    for (int d = 0; d < D; ++d) ss = fmaf(v[r][d], v[r][d], ss);
    float n = fmaxf(sqrtf(ss), EPS);
#pragma unroll
    for (int d = 0; d < D; ++d) v[r][d] = v[r][d] / n;
  }
  __syncthreads();

  float smax[RPT];
  int kb[RPT];
#pragma unroll
  for (int r = 0; r < RPT; ++r) { smax[r] = -3.4e38f; kb[r] = k0; }

#pragma unroll 2
  for (int kk = 0; kk < KCHUNK; ++kk) {
    const float4* __restrict__ er = &se4[kk * (D / 4)];  // wave-uniform -> broadcast
    float h = sh[kk];
    float a0 = -h, a1 = -h, a2 = -h, a3 = -h;
#pragma unroll
    for (int j = 0; j < D / 4; ++j) {
      float4 e = er[j];
      a0 = fmaf(v[0][4 * j + 0], e.x, a0);   // 4 independent chains, dep dist 8 cyc
      a1 = fmaf(v[1][4 * j + 0], e.x, a1);
      a2 = fmaf(v[2][4 * j + 0], e.x, a2);
      a3 = fmaf(v[3][4 * j + 0], e.x, a3);
      a0 = fmaf(v[0][4 * j + 1], e.y, a0);
      a1 = fmaf(v[1][4 * j + 1], e.y, a1);
      a2 = fmaf(v[2][4 * j + 1], e.y, a2);
      a3 = fmaf(v[3][4 * j + 1], e.y, a3);
      a0 = fmaf(v[0][4 * j + 2], e.z, a0);
      a1 = fmaf(v[1][4 * j + 2], e.z, a1);
      a2 = fmaf(v[2][4 * j + 2], e.z, a2);
      a3 = fmaf(v[3][4 * j + 2], e.z, a3);
      a0 = fmaf(v[0][4 * j + 3], e.w, a0);
      a1 = fmaf(v[1][4 * j + 3], e.w, a1);
      a2 = fmaf(v[2][4 * j + 3], e.w, a2);
      a3 = fmaf(v[3][4 * j + 3], e.w, a3);
    }
    int k = k0 + kk;
    if (a0 > smax[0]) { smax[0] = a0; kb[0] = k; }  // strict > keeps first max
    if (a1 > smax[1]) { smax[1] = a1; kb[1] = k; }  // (== first min of d)
    if (a2 > smax[2]) { smax[2] = a2; kb[2] = k; }
    if (a3 > smax[3]) { smax[3] = a3; kb[3] = k; }
  }

#pragma unroll
  for (int r = 0; r < RPT; ++r) {
    unsigned ord = __float_as_uint(smax[r]);
    ord = (ord & 0x80000000u) ? ~ord : (ord | 0x80000000u);  // monotone inc in s
    unsigned key = ~ord;                                     // monotone DEC in s
    unsigned long long pk =
        ((unsigned long long)key << 32) | (unsigned long long)(unsigned)kb[r];
    if (MODE == 0) {
      mp[(size_t)blockIdx.y * N + rowbase + r * 256 + t] = pk;  // coalesced
    } else {
      atomicMin(&mp[rowbase + r * 256 + t], pk);
    }
  }
}

__global__ __launch_bounds__(256) void k_epi(const float* __restrict__ z,
                                             const float* __restrict__ en,
                                             const unsigned long long* __restrict__ mp,
                                             int nsplit, int N,
                                             float* __restrict__ out_z,
                                             float* __restrict__ loss,
                                             float* __restrict__ out_idx,
                                             float scale) {
  int row = blockIdx.x * 256 + threadIdx.x;
  unsigned long long m = mp[row];
  for (int s = 1; s < nsplit; ++s) {
    unsigned long long m2 = mp[(size_t)s * N + row];
    m = (m2 < m) ? m2 : m;   // min key -> max s -> min d; tie -> min k
  }
  int kb = (int)(unsigned)(m & 0xFFFFFFFFull);
  out_idx[row] = (float)kb;  // whole out buffer read back as f32

  const float4* p = reinterpret_cast<const float4*>(z + (size_t)row * D);
  float4 q[D / 4];
#pragma unroll
  for (int j = 0; j < D / 4; ++j) q[j] = p[j];
  float ss = 0.f;
#pragma unroll
  for (int j = 0; j < D / 4; ++j)
    ss = fmaf(q[j].x, q[j].x, fmaf(q[j].y, q[j].y, fmaf(q[j].z, q[j].z, fmaf(q[j].w, q[j].w, ss))));
  float n = fmaxf(sqrtf(ss), EPS);

  const float4* ep = reinterpret_cast<const float4*>(en + (size_t)kb * D);
  float4* op = reinterpret_cast<float4*>(out_z + (size_t)row * D);
  float s = 0.f;
#pragma unroll
  for (int j = 0; j < D / 4; ++j) {
    float4 e = ep[j];
    float4 o;
    o.x = q[j].x + (e.x - q[j].x);  // STE forward value, reference op order
    o.y = q[j].y + (e.y - q[j].y);
    o.z = q[j].z + (e.z - q[j].z);
    o.w = q[j].w + (e.w - q[j].w);
    op[j] = o;
    float dx = e.x - q[j].x / n;  float dy = e.y - q[j].y / n;
    float dz = e.z - q[j].z / n;  float dw = e.w - q[j].w / n;
    s = fmaf(dx, dx, fmaf(dy, dy, fmaf(dz, dz, fmaf(dw, dw, s))));
  }

#pragma unroll
  for (int off = 32; off > 0; off >>= 1) s += __shfl_down(s, off, 64);
  __shared__ float wsum[4];
  int lane = threadIdx.x & 63, wid = threadIdx.x >> 6;
  if (lane == 0) wsum[wid] = s;
  __syncthreads();
  if (threadIdx.x == 0) {
    float tt = (wsum[0] + wsum[1]) + (wsum[2] + wsum[3]);
    atomicAdd(loss, tt * scale);
  }
}

extern "C" void kernel_launch(void* const* d_in, const int* in_sizes, int n_in,
                              void* d_out, int out_size, void* d_ws, size_t ws_size,
                              hipStream_t stream) {
  const float* z = (const float*)d_in[0];
  const float* emb = (const float*)d_in[1];
  const int N = in_sizes[0] / D;  // 32768
  const int K = in_sizes[1] / D;  // 8192

  float* out = (float*)d_out;
  float* out_z = out;                        // N*D
  float* loss = out + (size_t)N * D;         // 1
  float* out_idx = out + (size_t)N * D + 1;  // N

  float* en = (float*)d_ws;                  // K*D f32   (1 MB)
  float* en_h = en + (size_t)K * D;          // K f32     (32 KB)
  unsigned long long* mp =
      (unsigned long long*)(en_h + K);       // partials (8B-aligned offset)

  const int KSPLIT = K / KCHUNK;             // 32
  size_t need = (size_t)K * D * 4 + (size_t)K * 4 + (size_t)KSPLIT * N * 8;
  int mode = (ws_size != 0 && ws_size < need) ? 1 : 0;  // 1 = atomic fallback

  k_norm_emb<<<dim3((K + 255) / 256), 256, 0, stream>>>(
      emb, en, en_h, K, mp, mode ? N : 0, loss);

  if (mode == 0) {
    k_argmin<0><<<dim3(N / (256 * RPT), KSPLIT), 256, 0, stream>>>(z, en, en_h, mp, N);
    k_epi<<<dim3(N / 256), 256, 0, stream>>>(
        z, en, mp, KSPLIT, N, out_z, loss, out_idx, 1.25f / (float)((size_t)N * D));
  } else {
    k_argmin<1><<<dim3(N / (256 * RPT), KSPLIT), 256, 0, stream>>>(z, en, en_h, mp, N);
    k_epi<<<dim3(N / 256), 256, 0, stream>>>(
        z, en, mp, 1, N, out_z, loss, out_idx, 1.25f / (float)((size_t)N * D));
  }
}